// Round 7
// baseline (7472.469 us; speedup 1.0000x reference)
//
#include <hip/hip_runtime.h>

#define SEQ 1024
#define ISZ 6
#define HSZ 128
#define PRED 50
#define MROW 16
#define HP   136   // h row pitch in shorts (272B)
#define FP   132   // s_h1f row pitch in floats
#define XSLOT 120  // 65 used (64 x-steps + AR slot); rest pads LDS >80KB -> 1 block/CU

using f32x4  = __attribute__((ext_vector_type(4))) float;
using f32x2  = __attribute__((ext_vector_type(2))) float;
using bf16x8 = __attribute__((ext_vector_type(8))) short;

__device__ __forceinline__ short f2bf(float f){
  union { float f; unsigned u; } v; v.f = f;
  unsigned r = v.u + 0x7FFFu + ((v.u >> 16) & 1u);
  return (short)(r >> 16);
}
__device__ __forceinline__ float sigf(float x){
  float e = __builtin_amdgcn_exp2f(x * -1.4426950408889634f);
  return __builtin_amdgcn_rcpf(1.0f + e);
}
__device__ __forceinline__ float tanhf_(float x){
  float e = __builtin_amdgcn_exp2f(x * 2.8853900817779268f);
  return 1.0f - 2.0f * __builtin_amdgcn_rcpf(1.0f + e);
}

// v7 gate-split: 1024 threads = 16 waves, M=16 rows, 256 blocks.
// Wave wv: ug = wv&7 -> hidden units [16ug,16ug+16); role = wv>>3:
//   role0 owns gates {i,f}, role1 owns gates {g,o} + the c/h update.
// Per-wave weights: 3 matrices x 2 gates x 4kt = 96 VGPRs (vs 192 before).
// Rounds 1-6 proved: 8-wave blocks cap at 256 regs (2 waves/SIMD min) while
// true pressure was ~260 -> spill inevitable -> allocator fell back to 128.
// This structure needs ~126 regs -> fits the allocator's native 128 target.
// Gate exchange via s_gx in LDS (written before / read after one barrier);
// nothing extra is register-resident across barriers.
__global__ __launch_bounds__(1024, 1)
__attribute__((amdgpu_waves_per_eu(4, 4)))
void lstm_ar(
    const float* __restrict__ x,
    const float* __restrict__ w_ih0, const float* __restrict__ w_hh0,
    const float* __restrict__ b_ih0, const float* __restrict__ b_hh0,
    const float* __restrict__ w_ih1, const float* __restrict__ w_hh1,
    const float* __restrict__ b_ih1, const float* __restrict__ b_hh1,
    const float* __restrict__ fc_w, const float* __restrict__ fc_b,
    float* __restrict__ out)
{
  __shared__ short s_h0[2][MROW*HP];      // bf16 h0, double buffered
  __shared__ short s_h1[2][MROW*HP];
  __shared__ short s_x[XSLOT*MROW*8];     // x chunk (64 steps) + slot 64 = AR "cur"
  __shared__ short s_wih0[512*8];         // w_ih0 bf16, K padded 6->8
  __shared__ float s_gx[8][MROW][16][4];  // [ug][row][unit][iv,fv,gv,ov]
  __shared__ float s_h1f[MROW*FP];        // fp32 h1 for the fc head
  __shared__ float s_fcw[ISZ*HSZ];
  __shared__ float s_fcb[8];
  __shared__ short s_zpad[8];             // 16B of zeros for padded fragments

  const int tid  = threadIdx.x;
  const int wv   = tid >> 6;
  const int lane = tid & 63;
  const int l15  = lane & 15;
  const int lq   = lane >> 4;
  const int ug   = wv & 7;
  const int role = wv >> 3;
  const int u    = ug*16 + l15;           // this lane's hidden unit
  const int row0 = blockIdx.x * MROW;

  // ---- zero / stage LDS ----
  {
    short* p0 = &s_h0[0][0];
    short* p1 = &s_h1[0][0];
    for (int i = tid; i < 2*MROW*HP; i += 1024){ p0[i] = 0; p1[i] = 0; }
    for (int i = tid; i < 65*MROW*8; i += 1024) s_x[i] = 0;
    if (tid < 8){ s_zpad[tid] = 0; s_fcb[tid] = (tid < 6) ? fc_b[tid] : 0.f; }
    for (int i = tid; i < ISZ*HSZ; i += 1024) s_fcw[i] = fc_w[i];
    if (tid < 512){
      #pragma unroll
      for (int k = 0; k < 6; k++) s_wih0[tid*8 + k] = f2bf(w_ih0[tid*6 + k]);
      s_wih0[tid*8 + 6] = 0; s_wih0[tid*8 + 7] = 0;
    }
  }

  // ---- weights -> registers (bf16 B-fragments), 2 gates per wave ----
  // B-frag 16x16x32: col n = lane&15, k = (lane>>4)*8 + i  (B[k][n] = W[n][k])
  bf16x8 whh0f[2][4], wih1f[2][4], whh1f[2][4];
  float bias0[2], bias1[2];
  #pragma unroll
  for (int gg = 0; gg < 2; gg++){
    const int gate = role*2 + gg;
    const int c = gate*128 + u;
    bias0[gg] = b_ih0[c] + b_hh0[c];
    bias1[gg] = b_ih1[c] + b_hh1[c];
    #pragma unroll
    for (int kt = 0; kt < 4; kt++){
      const int off = c*HSZ + kt*32 + lq*8;
      bf16x8 r0, r1, r2;
      #pragma unroll
      for (int i = 0; i < 8; i++){
        r0[i] = f2bf(w_hh0[off + i]);
        r1[i] = f2bf(w_ih1[off + i]);
        r2[i] = f2bf(w_hh1[off + i]);
      }
      whh0f[gg][kt] = r0; wih1f[gg][kt] = r1; whh1f[gg][kt] = r2;
    }
  }

  float c0[4] = {0.f,0.f,0.f,0.f}, c1[4] = {0.f,0.f,0.f,0.f};
  __syncthreads();

  short* const hb0 = &s_h0[0][0];
  short* const hb1 = &s_h1[0][0];

  for (int t = 0; t < SEQ + PRED; ++t){
    // ---- stage 64 timesteps of x into LDS (bf16, K-padded) ----
    if (t < SEQ && (t & 63) == 0){
      for (int i = tid; i < MROW*64*ISZ; i += 1024){
        const int r   = i / (64*ISZ);
        const int rem = i % (64*ISZ);
        const int ts  = rem / ISZ;
        const int k   = rem % ISZ;
        const float v = x[(size_t)(row0 + r)*(SEQ*ISZ) + (size_t)(t + ts)*ISZ + k];
        s_x[(ts*MROW + r)*8 + k] = f2bf(v);
      }
      __syncthreads();
    }
    const int tt = (t < SEQ) ? (t & 63) : 64;
    const int pb = t & 1, qb = pb ^ 1;
    short* const h0q = hb0 + qb*(MROW*HP);
    short* const h0p = hb0 + pb*(MROW*HP);
    short* const h1q = hb1 + qb*(MROW*HP);
    short* const h1p = hb1 + pb*(MROW*HP);

    // ---- layer 0: gates = x_t @ w_ih0^T + h0 @ w_hh0^T + b0 (2 gates/wave) --
    const short* pax = (lq == 0) ? (s_x + (tt*MROW + l15)*8) : s_zpad;
    const bf16x8 ax = *(const bf16x8*)pax;

    f32x4 acc0, acc1;
    {
      const int g0 = role*2, g1 = role*2 + 1;
      const short* pw0 = (lq == 0) ? (s_wih0 + (g0*128 + u)*8) : s_zpad;
      const short* pw1 = (lq == 0) ? (s_wih0 + (g1*128 + u)*8) : s_zpad;
      f32x4 ci0, ci1;
      ci0[0]=bias0[0]; ci0[1]=bias0[0]; ci0[2]=bias0[0]; ci0[3]=bias0[0];
      ci1[0]=bias0[1]; ci1[1]=bias0[1]; ci1[2]=bias0[1]; ci1[3]=bias0[1];
      acc0 = __builtin_amdgcn_mfma_f32_16x16x32_bf16(ax, *(const bf16x8*)pw0, ci0, 0, 0, 0);
      acc1 = __builtin_amdgcn_mfma_f32_16x16x32_bf16(ax, *(const bf16x8*)pw1, ci1, 0, 0, 0);
    }
    #pragma unroll
    for (int kt = 0; kt < 4; kt++){
      const bf16x8 a = *(const bf16x8*)(h0q + l15*HP + (kt*4 + lq)*8);
      acc0 = __builtin_amdgcn_mfma_f32_16x16x32_bf16(a, whh0f[0][kt], acc0, 0, 0, 0);
      acc1 = __builtin_amdgcn_mfma_f32_16x16x32_bf16(a, whh0f[1][kt], acc1, 0, 0, 0);
    }
    if (role == 0){
      #pragma unroll
      for (int j = 0; j < 4; j++){
        const int r = lq*4 + j;
        f32x2 w; w[0] = sigf(acc0[j]); w[1] = sigf(acc1[j]);       // iv, fv
        *(f32x2*)&s_gx[ug][r][l15][0] = w;
      }
    } else {
      #pragma unroll
      for (int j = 0; j < 4; j++){
        const int r = lq*4 + j;
        f32x2 w; w[0] = tanhf_(acc0[j]); w[1] = sigf(acc1[j]);     // gv, ov
        *(f32x2*)&s_gx[ug][r][l15][2] = w;
      }
    }
    __syncthreads();
    if (role == 1){
      #pragma unroll
      for (int j = 0; j < 4; j++){
        const int r = lq*4 + j;
        const f32x4 g4 = *(const f32x4*)&s_gx[ug][r][l15][0];      // iv,fv,gv,ov
        c0[j] = g4[1]*c0[j] + g4[0]*g4[2];
        const float h = g4[3] * tanhf_(c0[j]);
        h0p[r*HP + u] = f2bf(h);
      }
    }
    __syncthreads();

    // ---- layer 1: gates = h0_new @ w_ih1^T + h1 @ w_hh1^T + b1 ----
    acc0[0]=bias1[0]; acc0[1]=bias1[0]; acc0[2]=bias1[0]; acc0[3]=bias1[0];
    acc1[0]=bias1[1]; acc1[1]=bias1[1]; acc1[2]=bias1[1]; acc1[3]=bias1[1];
    #pragma unroll
    for (int kt = 0; kt < 4; kt++){
      const bf16x8 a = *(const bf16x8*)(h0p + l15*HP + (kt*4 + lq)*8);
      acc0 = __builtin_amdgcn_mfma_f32_16x16x32_bf16(a, wih1f[0][kt], acc0, 0, 0, 0);
      acc1 = __builtin_amdgcn_mfma_f32_16x16x32_bf16(a, wih1f[1][kt], acc1, 0, 0, 0);
    }
    #pragma unroll
    for (int kt = 0; kt < 4; kt++){
      const bf16x8 a = *(const bf16x8*)(h1q + l15*HP + (kt*4 + lq)*8);
      acc0 = __builtin_amdgcn_mfma_f32_16x16x32_bf16(a, whh1f[0][kt], acc0, 0, 0, 0);
      acc1 = __builtin_amdgcn_mfma_f32_16x16x32_bf16(a, whh1f[1][kt], acc1, 0, 0, 0);
    }
    if (role == 0){
      #pragma unroll
      for (int j = 0; j < 4; j++){
        const int r = lq*4 + j;
        f32x2 w; w[0] = sigf(acc0[j]); w[1] = sigf(acc1[j]);       // iv, fv
        *(f32x2*)&s_gx[ug][r][l15][0] = w;
      }
    } else {
      #pragma unroll
      for (int j = 0; j < 4; j++){
        const int r = lq*4 + j;
        f32x2 w; w[0] = tanhf_(acc0[j]); w[1] = sigf(acc1[j]);     // gv, ov
        *(f32x2*)&s_gx[ug][r][l15][2] = w;
      }
    }
    __syncthreads();
    const bool dofc = (t >= SEQ - 1);
    if (role == 1){
      #pragma unroll
      for (int j = 0; j < 4; j++){
        const int r = lq*4 + j;
        const f32x4 g4 = *(const f32x4*)&s_gx[ug][r][l15][0];
        c1[j] = g4[1]*c1[j] + g4[0]*g4[2];
        const float h = g4[3] * tanhf_(c1[j]);
        h1p[r*HP + u] = f2bf(h);
        if (dofc) s_h1f[r*FP + u] = h;
      }
    }
    __syncthreads();

    // ---- fc head: pred = tanh(h1 @ fc_w^T + fc_b); feeds AR input ----
    if (dofc){
      if (tid < 96){
        const int r  = tid / 6;
        const int ii = tid % 6;
        const f32x4* hv = (const f32x4*)(s_h1f + r*FP);
        const f32x4* wf = (const f32x4*)(s_fcw + ii*128);
        float sacc = 0.f;
        #pragma unroll
        for (int kk = 0; kk < 32; kk++){
          const f32x4 a = hv[kk], b = wf[kk];
          sacc += a[0]*b[0] + a[1]*b[1] + a[2]*b[2] + a[3]*b[3];
        }
        const float pred = tanhf_(s_fcb[ii] + sacc);
        s_x[(64*MROW + r)*8 + ii] = f2bf(pred);   // next step's input
        if (t >= SEQ)
          out[(size_t)(row0 + r)*(PRED*ISZ) + (size_t)(t - SEQ)*ISZ + ii] = pred;
      }
      __syncthreads();
    }
  }
}

extern "C" void kernel_launch(void* const* d_in, const int* in_sizes, int n_in,
                              void* d_out, int out_size, void* d_ws, size_t ws_size,
                              hipStream_t stream) {
  const float* x     = (const float*)d_in[0];
  const float* w_ih0 = (const float*)d_in[1];
  const float* w_hh0 = (const float*)d_in[2];
  const float* b_ih0 = (const float*)d_in[3];
  const float* b_hh0 = (const float*)d_in[4];
  const float* w_ih1 = (const float*)d_in[5];
  const float* w_hh1 = (const float*)d_in[6];
  const float* b_ih1 = (const float*)d_in[7];
  const float* b_hh1 = (const float*)d_in[8];
  const float* fc_w  = (const float*)d_in[9];
  const float* fc_b  = (const float*)d_in[10];
  float* out = (float*)d_out;

  const int Btot = in_sizes[0] / (SEQ * ISZ);   // 4096
  const int nblk = Btot / MROW;                 // 256

  lstm_ar<<<dim3(nblk), dim3(1024), 0, stream>>>(
      x, w_ih0, w_hh0, b_ih0, b_hh0, w_ih1, w_hh1, b_ih1, b_hh1, fc_w, fc_b, out);
}

// Round 8
// 4236.585 us; speedup vs baseline: 1.7638x; 1.7638x over previous
//
#include <hip/hip_runtime.h>

#define SEQ 1024
#define ISZ 6
#define HSZ 128
#define PRED 50
#define MROW 16
#define HP   136   // h row pitch in shorts (272B)
#define FP   132   // s_h1f row pitch in floats
#define XSLOT 180  // s_x slots: 65 used; rest inflates LDS to 83KB -> 1 block/CU

using f32x4  = __attribute__((ext_vector_type(4))) float;
using bf16x8 = __attribute__((ext_vector_type(8))) short;

__device__ __forceinline__ short f2bf(float f){
  union { float f; unsigned u; } v; v.f = f;
  unsigned r = v.u + 0x7FFFu + ((v.u >> 16) & 1u);
  return (short)(r >> 16);
}
__device__ __forceinline__ float sigf(float x){
  float e = __builtin_amdgcn_exp2f(x * -1.4426950408889634f);
  return __builtin_amdgcn_rcpf(1.0f + e);
}
__device__ __forceinline__ float tanhf_(float x){
  float e = __builtin_amdgcn_exp2f(x * 2.8853900817779268f);
  return 1.0f - 2.0f * __builtin_amdgcn_rcpf(1.0f + e);
}

// One block = 512 threads = 8 waves, one block per CU, M=16 batch rows.
// Wave w owns hidden units [16w, 16w+16) of BOTH layers. Weights w_hh0 /
// w_ih1 / w_hh1 live in VGPRs as MFMA B-fragments (192 regs/thread).
//
// ATTRIBUTE EXPERIMENT (round 8): NO __launch_bounds__, NO waves_per_eu —
// only amdgpu_flat_work_group_size(512,512). Evidence: every launch_bounds
// variant produced grant = 65536/threads (128 @ 512thr, 64 @ 1024thr) and
// spilled all weights (WRITE_SIZE ~107MB scratch). learn_hip m214 reports a
// 512-thread kernel at 249 VGPR / 0 spill on this toolchain WITHOUT
// launch_bounds -> the hint stack itself appears to pin the 128 cap. LDS is
// held at 83KB so the LDS-derived occupancy (1 block/CU -> 2 waves/SIMD)
// implies a 256-reg budget for the default heuristic.
__global__
__attribute__((amdgpu_flat_work_group_size(512, 512)))
void lstm_ar(
    const float* __restrict__ x,
    const float* __restrict__ w_ih0, const float* __restrict__ w_hh0,
    const float* __restrict__ b_ih0, const float* __restrict__ b_hh0,
    const float* __restrict__ w_ih1, const float* __restrict__ w_hh1,
    const float* __restrict__ b_ih1, const float* __restrict__ b_hh1,
    const float* __restrict__ fc_w, const float* __restrict__ fc_b,
    float* __restrict__ out)
{
  __shared__ short s_h0[2][MROW*HP];    // bf16 h0, double buffered, padded pitch
  __shared__ short s_h1[2][MROW*HP];
  __shared__ short s_x[XSLOT*MROW*8];   // x chunk (64 steps) + slot 64 = AR "cur"
  __shared__ short s_wih0[512*8];       // w_ih0 bf16, K padded 6->8
  __shared__ float s_h1f[MROW*FP];      // fp32 h1 for the fc head
  __shared__ float s_fcw[ISZ*HSZ];
  __shared__ float s_fcb[8];
  __shared__ short s_zpad[8];           // 16B of zeros for padded fragments

  const int tid  = threadIdx.x;
  const int wv   = tid >> 6;
  const int lane = tid & 63;
  const int l15  = lane & 15;
  const int lq   = lane >> 4;
  const int U    = wv * 16;
  const int u    = U + l15;             // this lane's hidden unit (acc/B-frag col)
  const int row0 = blockIdx.x * MROW;

  // ---- zero / stage LDS ----
  {
    short* p0 = &s_h0[0][0];
    short* p1 = &s_h1[0][0];
    for (int i = tid; i < 2*MROW*HP; i += 512){ p0[i] = 0; p1[i] = 0; }
    for (int i = tid; i < 65*MROW*8; i += 512) s_x[i] = 0;
    if (tid < 8){ s_zpad[tid] = 0; s_fcb[tid] = (tid < 6) ? fc_b[tid] : 0.f; }
    for (int i = tid; i < ISZ*HSZ; i += 512) s_fcw[i] = fc_w[i];
    {
      #pragma unroll
      for (int k = 0; k < 6; k++) s_wih0[tid*8 + k] = f2bf(w_ih0[tid*6 + k]);
      s_wih0[tid*8 + 6] = 0; s_wih0[tid*8 + 7] = 0;
    }
  }

  // ---- weights -> registers (bf16 B-fragments) ----
  // B-frag for 16x16x32: col n = lane&15, k = (lane>>4)*8 + i  (B[k][n] = W[n][k])
  bf16x8 whh0f[4][4], wih1f[4][4], whh1f[4][4];
  float bias0[4], bias1[4];
  #pragma unroll
  for (int g = 0; g < 4; g++){
    const int c = g*128 + u;
    bias0[g] = b_ih0[c] + b_hh0[c];
    bias1[g] = b_ih1[c] + b_hh1[c];
    #pragma unroll
    for (int kt = 0; kt < 4; kt++){
      const int off = c*HSZ + kt*32 + lq*8;
      bf16x8 r0, r1, r2;
      #pragma unroll
      for (int i = 0; i < 8; i++){
        r0[i] = f2bf(w_hh0[off + i]);
        r1[i] = f2bf(w_ih1[off + i]);
        r2[i] = f2bf(w_hh1[off + i]);
      }
      whh0f[g][kt] = r0; wih1f[g][kt] = r1; whh1f[g][kt] = r2;
    }
  }

  float c0[4] = {0.f,0.f,0.f,0.f}, c1[4] = {0.f,0.f,0.f,0.f};
  __syncthreads();

  for (int t = 0; t < SEQ + PRED; ++t){
    // ---- stage 64 timesteps of x into LDS (bf16, K-padded) ----
    if (t < SEQ && (t & 63) == 0){
      for (int i = tid; i < MROW*64*ISZ; i += 512){
        const int r   = i / (64*ISZ);
        const int rem = i % (64*ISZ);
        const int ts  = rem / ISZ;
        const int k   = rem % ISZ;
        const float v = x[(size_t)(row0 + r)*(SEQ*ISZ) + (size_t)(t + ts)*ISZ + k];
        s_x[(ts*MROW + r)*8 + k] = f2bf(v);
      }
      __syncthreads();
    }
    const int tt = (t < SEQ) ? (t & 63) : 64;
    const int pb = t & 1, qb = pb ^ 1;

    // ---- layer 0: gates = x_t @ w_ih0^T + h0 @ w_hh0^T + b0 ----
    const short* pax = (lq == 0) ? (s_x + (tt*MROW + l15)*8) : s_zpad;
    const bf16x8 ax = *(const bf16x8*)pax;

    f32x4 acc[4];
    #pragma unroll
    for (int g = 0; g < 4; g++){
      const short* pw = (lq == 0) ? (s_wih0 + (g*128 + u)*8) : s_zpad;
      const bf16x8 bw = *(const bf16x8*)pw;
      f32x4 ci; ci[0] = bias0[g]; ci[1] = bias0[g]; ci[2] = bias0[g]; ci[3] = bias0[g];
      acc[g] = __builtin_amdgcn_mfma_f32_16x16x32_bf16(ax, bw, ci, 0, 0, 0);
    }
    #pragma unroll
    for (int kt = 0; kt < 4; kt++){
      const int s = kt*4 + lq;
      const short* pa = s_h0[qb] + l15*HP + s*8;
      const bf16x8 a = *(const bf16x8*)pa;
      #pragma unroll
      for (int g = 0; g < 4; g++)
        acc[g] = __builtin_amdgcn_mfma_f32_16x16x32_bf16(a, whh0f[g][kt], acc[g], 0, 0, 0);
    }
    #pragma unroll
    for (int j = 0; j < 4; j++){
      const float iv = sigf(acc[0][j]);
      const float fv = sigf(acc[1][j]);
      const float gv = tanhf_(acc[2][j]);
      const float ov = sigf(acc[3][j]);
      c0[j] = fv*c0[j] + iv*gv;
      const float h = ov * tanhf_(c0[j]);
      const int r = lq*4 + j;
      s_h0[pb][r*HP + u] = f2bf(h);
    }
    __syncthreads();

    // ---- layer 1: gates = h0_new @ w_ih1^T + h1 @ w_hh1^T + b1 ----
    #pragma unroll
    for (int g = 0; g < 4; g++){
      acc[g][0] = bias1[g]; acc[g][1] = bias1[g]; acc[g][2] = bias1[g]; acc[g][3] = bias1[g];
    }
    #pragma unroll
    for (int kt = 0; kt < 4; kt++){
      const int s = kt*4 + lq;
      const short* pa = s_h0[pb] + l15*HP + s*8;
      const bf16x8 a = *(const bf16x8*)pa;
      #pragma unroll
      for (int g = 0; g < 4; g++)
        acc[g] = __builtin_amdgcn_mfma_f32_16x16x32_bf16(a, wih1f[g][kt], acc[g], 0, 0, 0);
    }
    #pragma unroll
    for (int kt = 0; kt < 4; kt++){
      const int s = kt*4 + lq;
      const short* pa = s_h1[qb] + l15*HP + s*8;
      const bf16x8 a = *(const bf16x8*)pa;
      #pragma unroll
      for (int g = 0; g < 4; g++)
        acc[g] = __builtin_amdgcn_mfma_f32_16x16x32_bf16(a, whh1f[g][kt], acc[g], 0, 0, 0);
    }
    const bool dofc = (t >= SEQ - 1);
    #pragma unroll
    for (int j = 0; j < 4; j++){
      const float iv = sigf(acc[0][j]);
      const float fv = sigf(acc[1][j]);
      const float gv = tanhf_(acc[2][j]);
      const float ov = sigf(acc[3][j]);
      c1[j] = fv*c1[j] + iv*gv;
      const float h = ov * tanhf_(c1[j]);
      const int r = lq*4 + j;
      s_h1[pb][r*HP + u] = f2bf(h);
      if (dofc) s_h1f[r*FP + u] = h;
    }
    __syncthreads();

    // ---- fc head: pred = tanh(h1 @ fc_w^T + fc_b); feeds AR input ----
    if (dofc){
      if (tid < 96){
        const int r  = tid / 6;
        const int ii = tid % 6;
        const f32x4* hv = (const f32x4*)(s_h1f + r*FP);
        const f32x4* wf = (const f32x4*)(s_fcw + ii*128);
        float sacc = 0.f;
        #pragma unroll
        for (int kk = 0; kk < 32; kk++){
          const f32x4 a = hv[kk], b = wf[kk];
          sacc += a[0]*b[0] + a[1]*b[1] + a[2]*b[2] + a[3]*b[3];
        }
        const float pred = tanhf_(s_fcb[ii] + sacc);
        s_x[(64*MROW + r)*8 + ii] = f2bf(pred);   // next step's input
        if (t >= SEQ)
          out[(size_t)(row0 + r)*(PRED*ISZ) + (size_t)(t - SEQ)*ISZ + ii] = pred;
      }
      __syncthreads();
    }
  }
}

extern "C" void kernel_launch(void* const* d_in, const int* in_sizes, int n_in,
                              void* d_out, int out_size, void* d_ws, size_t ws_size,
                              hipStream_t stream) {
  const float* x     = (const float*)d_in[0];
  const float* w_ih0 = (const float*)d_in[1];
  const float* w_hh0 = (const float*)d_in[2];
  const float* b_ih0 = (const float*)d_in[3];
  const float* b_hh0 = (const float*)d_in[4];
  const float* w_ih1 = (const float*)d_in[5];
  const float* w_hh1 = (const float*)d_in[6];
  const float* b_ih1 = (const float*)d_in[7];
  const float* b_hh1 = (const float*)d_in[8];
  const float* fc_w  = (const float*)d_in[9];
  const float* fc_b  = (const float*)d_in[10];
  float* out = (float*)d_out;

  const int Btot = in_sizes[0] / (SEQ * ISZ);   // 4096
  const int nblk = Btot / MROW;                 // 256

  lstm_ar<<<dim3(nblk), dim3(512), 0, stream>>>(
      x, w_ih0, w_hh0, b_ih0, b_hh0, w_ih1, w_hh1, b_ih1, b_hh1, fc_w, fc_b, out);
}

// Round 9
// 4235.413 us; speedup vs baseline: 1.7643x; 1.0003x over previous
//
#include <hip/hip_runtime.h>

#define SEQ 1024
#define ISZ 6
#define HSZ 128
#define PRED 50
#define MROW 16
#define HP   136   // h row pitch in shorts (272B)
#define FP   132   // s_h1f row pitch in floats
#define XSLOT 180  // s_x slots: 65 used; rest inflates LDS to 83KB -> 1 block/CU

using f32x4  = __attribute__((ext_vector_type(4))) float;
using bf16x8 = __attribute__((ext_vector_type(8))) short;

__device__ __forceinline__ short f2bf(float f){
  union { float f; unsigned u; } v; v.f = f;
  unsigned r = v.u + 0x7FFFu + ((v.u >> 16) & 1u);
  return (short)(r >> 16);
}
__device__ __forceinline__ float sigf(float x){
  float e = __builtin_amdgcn_exp2f(x * -1.4426950408889634f);
  return __builtin_amdgcn_rcpf(1.0f + e);
}
__device__ __forceinline__ float tanhf_(float x){
  float e = __builtin_amdgcn_exp2f(x * 2.8853900817779268f);
  return 1.0f - 2.0f * __builtin_amdgcn_rcpf(1.0f + e);
}

// ROUND 9 EXPERIMENT: direct VGPR-budget override via amdgpu_num_vgpr.
// Evidence so far: grant = 65536/block_threads in EVERY config (launch_bounds
// (512,2)/(512,1), waves_per_eu(2,2)/(4,4), bare flat_work_group_size, real
// 83KB LDS) -> occupancy HINTS are never consulted for the budget. num_vgpr
// is a direct request the backend reads before its heuristic; 512thr @ 256
// VGPR = 2 waves/SIMD is legal. __has_attribute-guarded: if unsupported we
// degrade exactly to round 8 (passing, 4.2ms), not a compile error.
#if defined(__has_attribute)
#if __has_attribute(amdgpu_num_vgpr)
#define NUM_VGPR_ATTR __attribute__((amdgpu_num_vgpr(256)))
#else
#define NUM_VGPR_ATTR
#endif
#else
#define NUM_VGPR_ATTR
#endif

// One block = 512 threads = 8 waves, one block per CU, M=16 batch rows.
// Wave w owns hidden units [16w, 16w+16) of BOTH layers. Weights w_hh0 /
// w_ih1 / w_hh1 live in VGPRs as MFMA B-fragments (192 regs/thread), builtin
// MFMAs only (round-3/8 arithmetic, absmax 4.9e-4).
__global__
__attribute__((amdgpu_flat_work_group_size(512, 512)))
NUM_VGPR_ATTR
void lstm_ar(
    const float* __restrict__ x,
    const float* __restrict__ w_ih0, const float* __restrict__ w_hh0,
    const float* __restrict__ b_ih0, const float* __restrict__ b_hh0,
    const float* __restrict__ w_ih1, const float* __restrict__ w_hh1,
    const float* __restrict__ b_ih1, const float* __restrict__ b_hh1,
    const float* __restrict__ fc_w, const float* __restrict__ fc_b,
    float* __restrict__ out)
{
  __shared__ short s_h0[2][MROW*HP];    // bf16 h0, double buffered, padded pitch
  __shared__ short s_h1[2][MROW*HP];
  __shared__ short s_x[XSLOT*MROW*8];   // x chunk (64 steps) + slot 64 = AR "cur"
  __shared__ short s_wih0[512*8];       // w_ih0 bf16, K padded 6->8
  __shared__ float s_h1f[MROW*FP];      // fp32 h1 for the fc head
  __shared__ float s_fcw[ISZ*HSZ];
  __shared__ float s_fcb[8];
  __shared__ short s_zpad[8];           // 16B of zeros for padded fragments

  const int tid  = threadIdx.x;
  const int wv   = tid >> 6;
  const int lane = tid & 63;
  const int l15  = lane & 15;
  const int lq   = lane >> 4;
  const int U    = wv * 16;
  const int u    = U + l15;             // this lane's hidden unit (acc/B-frag col)
  const int row0 = blockIdx.x * MROW;

  // ---- zero / stage LDS ----
  {
    short* p0 = &s_h0[0][0];
    short* p1 = &s_h1[0][0];
    for (int i = tid; i < 2*MROW*HP; i += 512){ p0[i] = 0; p1[i] = 0; }
    for (int i = tid; i < 65*MROW*8; i += 512) s_x[i] = 0;
    if (tid < 8){ s_zpad[tid] = 0; s_fcb[tid] = (tid < 6) ? fc_b[tid] : 0.f; }
    for (int i = tid; i < ISZ*HSZ; i += 512) s_fcw[i] = fc_w[i];
    {
      #pragma unroll
      for (int k = 0; k < 6; k++) s_wih0[tid*8 + k] = f2bf(w_ih0[tid*6 + k]);
      s_wih0[tid*8 + 6] = 0; s_wih0[tid*8 + 7] = 0;
    }
  }

  // ---- weights -> registers (bf16 B-fragments) ----
  // B-frag for 16x16x32: col n = lane&15, k = (lane>>4)*8 + i  (B[k][n] = W[n][k])
  bf16x8 whh0f[4][4], wih1f[4][4], whh1f[4][4];
  float bias0[4], bias1[4];
  #pragma unroll
  for (int g = 0; g < 4; g++){
    const int c = g*128 + u;
    bias0[g] = b_ih0[c] + b_hh0[c];
    bias1[g] = b_ih1[c] + b_hh1[c];
    #pragma unroll
    for (int kt = 0; kt < 4; kt++){
      const int off = c*HSZ + kt*32 + lq*8;
      bf16x8 r0, r1, r2;
      #pragma unroll
      for (int i = 0; i < 8; i++){
        r0[i] = f2bf(w_hh0[off + i]);
        r1[i] = f2bf(w_ih1[off + i]);
        r2[i] = f2bf(w_hh1[off + i]);
      }
      whh0f[g][kt] = r0; wih1f[g][kt] = r1; whh1f[g][kt] = r2;
    }
  }

  float c0[4] = {0.f,0.f,0.f,0.f}, c1[4] = {0.f,0.f,0.f,0.f};
  __syncthreads();

  for (int t = 0; t < SEQ + PRED; ++t){
    // ---- stage 64 timesteps of x into LDS (bf16, K-padded) ----
    if (t < SEQ && (t & 63) == 0){
      for (int i = tid; i < MROW*64*ISZ; i += 512){
        const int r   = i / (64*ISZ);
        const int rem = i % (64*ISZ);
        const int ts  = rem / ISZ;
        const int k   = rem % ISZ;
        const float v = x[(size_t)(row0 + r)*(SEQ*ISZ) + (size_t)(t + ts)*ISZ + k];
        s_x[(ts*MROW + r)*8 + k] = f2bf(v);
      }
      __syncthreads();
    }
    const int tt = (t < SEQ) ? (t & 63) : 64;
    const int pb = t & 1, qb = pb ^ 1;

    // ---- layer 0: gates = x_t @ w_ih0^T + h0 @ w_hh0^T + b0 ----
    const short* pax = (lq == 0) ? (s_x + (tt*MROW + l15)*8) : s_zpad;
    const bf16x8 ax = *(const bf16x8*)pax;

    f32x4 acc[4];
    #pragma unroll
    for (int g = 0; g < 4; g++){
      const short* pw = (lq == 0) ? (s_wih0 + (g*128 + u)*8) : s_zpad;
      const bf16x8 bw = *(const bf16x8*)pw;
      f32x4 ci; ci[0] = bias0[g]; ci[1] = bias0[g]; ci[2] = bias0[g]; ci[3] = bias0[g];
      acc[g] = __builtin_amdgcn_mfma_f32_16x16x32_bf16(ax, bw, ci, 0, 0, 0);
    }
    #pragma unroll
    for (int kt = 0; kt < 4; kt++){
      const int s = kt*4 + lq;
      const short* pa = s_h0[qb] + l15*HP + s*8;
      const bf16x8 a = *(const bf16x8*)pa;
      #pragma unroll
      for (int g = 0; g < 4; g++)
        acc[g] = __builtin_amdgcn_mfma_f32_16x16x32_bf16(a, whh0f[g][kt], acc[g], 0, 0, 0);
    }
    #pragma unroll
    for (int j = 0; j < 4; j++){
      const float iv = sigf(acc[0][j]);
      const float fv = sigf(acc[1][j]);
      const float gv = tanhf_(acc[2][j]);
      const float ov = sigf(acc[3][j]);
      c0[j] = fv*c0[j] + iv*gv;
      const float h = ov * tanhf_(c0[j]);
      const int r = lq*4 + j;
      s_h0[pb][r*HP + u] = f2bf(h);
    }
    __syncthreads();

    // ---- layer 1: gates = h0_new @ w_ih1^T + h1 @ w_hh1^T + b1 ----
    #pragma unroll
    for (int g = 0; g < 4; g++){
      acc[g][0] = bias1[g]; acc[g][1] = bias1[g]; acc[g][2] = bias1[g]; acc[g][3] = bias1[g];
    }
    #pragma unroll
    for (int kt = 0; kt < 4; kt++){
      const int s = kt*4 + lq;
      const short* pa = s_h0[pb] + l15*HP + s*8;
      const bf16x8 a = *(const bf16x8*)pa;
      #pragma unroll
      for (int g = 0; g < 4; g++)
        acc[g] = __builtin_amdgcn_mfma_f32_16x16x32_bf16(a, wih1f[g][kt], acc[g], 0, 0, 0);
    }
    #pragma unroll
    for (int kt = 0; kt < 4; kt++){
      const int s = kt*4 + lq;
      const short* pa = s_h1[qb] + l15*HP + s*8;
      const bf16x8 a = *(const bf16x8*)pa;
      #pragma unroll
      for (int g = 0; g < 4; g++)
        acc[g] = __builtin_amdgcn_mfma_f32_16x16x32_bf16(a, whh1f[g][kt], acc[g], 0, 0, 0);
    }
    const bool dofc = (t >= SEQ - 1);
    #pragma unroll
    for (int j = 0; j < 4; j++){
      const float iv = sigf(acc[0][j]);
      const float fv = sigf(acc[1][j]);
      const float gv = tanhf_(acc[2][j]);
      const float ov = sigf(acc[3][j]);
      c1[j] = fv*c1[j] + iv*gv;
      const float h = ov * tanhf_(c1[j]);
      const int r = lq*4 + j;
      s_h1[pb][r*HP + u] = f2bf(h);
      if (dofc) s_h1f[r*FP + u] = h;
    }
    __syncthreads();

    // ---- fc head: pred = tanh(h1 @ fc_w^T + fc_b); feeds AR input ----
    if (dofc){
      if (tid < 96){
        const int r  = tid / 6;
        const int ii = tid % 6;
        const f32x4* hv = (const f32x4*)(s_h1f + r*FP);
        const f32x4* wf = (const f32x4*)(s_fcw + ii*128);
        float sacc = 0.f;
        #pragma unroll
        for (int kk = 0; kk < 32; kk++){
          const f32x4 a = hv[kk], b = wf[kk];
          sacc += a[0]*b[0] + a[1]*b[1] + a[2]*b[2] + a[3]*b[3];
        }
        const float pred = tanhf_(s_fcb[ii] + sacc);
        s_x[(64*MROW + r)*8 + ii] = f2bf(pred);   // next step's input
        if (t >= SEQ)
          out[(size_t)(row0 + r)*(PRED*ISZ) + (size_t)(t - SEQ)*ISZ + ii] = pred;
      }
      __syncthreads();
    }
  }
}

extern "C" void kernel_launch(void* const* d_in, const int* in_sizes, int n_in,
                              void* d_out, int out_size, void* d_ws, size_t ws_size,
                              hipStream_t stream) {
  const float* x     = (const float*)d_in[0];
  const float* w_ih0 = (const float*)d_in[1];
  const float* w_hh0 = (const float*)d_in[2];
  const float* b_ih0 = (const float*)d_in[3];
  const float* b_hh0 = (const float*)d_in[4];
  const float* w_ih1 = (const float*)d_in[5];
  const float* w_hh1 = (const float*)d_in[6];
  const float* b_ih1 = (const float*)d_in[7];
  const float* b_hh1 = (const float*)d_in[8];
  const float* fc_w  = (const float*)d_in[9];
  const float* fc_b  = (const float*)d_in[10];
  float* out = (float*)d_out;

  const int Btot = in_sizes[0] / (SEQ * ISZ);   // 4096
  const int nblk = Btot / MROW;                 // 256

  lstm_ar<<<dim3(nblk), dim3(512), 0, stream>>>(
      x, w_ih0, w_hh0, b_ih0, b_hh0, w_ih1, w_hh1, b_ih1, b_hh1, fc_w, fc_b, out);
}

// Round 10
// 3675.261 us; speedup vs baseline: 2.0332x; 1.1524x over previous
//
#include <hip/hip_runtime.h>

#define SEQ 1024
#define ISZ 6
#define HSZ 128
#define PRED 50
#define MROW 16
#define HP   136   // h row pitch in shorts (272B)
#define FP   132   // s_h1f row pitch in floats
#define XSLOT 180  // s_x slots: 65 used; rest inflates LDS to 83KB -> 1 block/CU

using f32x4  = __attribute__((ext_vector_type(4))) float;
using bf16x8 = __attribute__((ext_vector_type(8))) short;

__device__ __forceinline__ short f2bf(float f){
  union { float f; unsigned u; } v; v.f = f;
  unsigned r = v.u + 0x7FFFu + ((v.u >> 16) & 1u);
  return (short)(r >> 16);
}
__device__ __forceinline__ float sigf(float x){
  float e = __builtin_amdgcn_exp2f(x * -1.4426950408889634f);
  return __builtin_amdgcn_rcpf(1.0f + e);
}
__device__ __forceinline__ float tanhf_(float x){
  float e = __builtin_amdgcn_exp2f(x * 2.8853900817779268f);
  return 1.0f - 2.0f * __builtin_amdgcn_rcpf(1.0f + e);
}

// ROUND 10: anti-spill PIN. Empty asm with "+v" marks each weight fragment as
// REDEFINED every loop iteration -> spilling it would cost a store+reload per
// step (not a one-time store) -> the allocator's spill-cost model flips from
// "spill 192 read-only regs, run at 128" (rounds 1-9, WRITE_SIZE 107MB) to
// "allocate ~252 regs at 2 waves/SIMD". Evidence the cap is NOT hard: m214
// (512thr, 249 VGPR, 0 spill) and m97 (164v+64a) on this same toolchain.
// Zero instructions emitted; arithmetic bit-identical to round 8 (passing).
#define PIN(v) asm volatile("" : "+v"(v))

// One block = 512 threads = 8 waves, one block per CU, M=16 batch rows.
// Wave w owns hidden units [16w, 16w+16) of BOTH layers. Weights w_hh0 /
// w_ih1 / w_hh1 live in VGPRs as MFMA B-fragments (192 regs/thread), builtin
// MFMAs only. LDS held at 83KB -> 1 block/CU -> 2 waves/SIMD occupancy.
__global__
__attribute__((amdgpu_flat_work_group_size(512, 512)))
void lstm_ar(
    const float* __restrict__ x,
    const float* __restrict__ w_ih0, const float* __restrict__ w_hh0,
    const float* __restrict__ b_ih0, const float* __restrict__ b_hh0,
    const float* __restrict__ w_ih1, const float* __restrict__ w_hh1,
    const float* __restrict__ b_ih1, const float* __restrict__ b_hh1,
    const float* __restrict__ fc_w, const float* __restrict__ fc_b,
    float* __restrict__ out)
{
  __shared__ short s_h0[2][MROW*HP];    // bf16 h0, double buffered, padded pitch
  __shared__ short s_h1[2][MROW*HP];
  __shared__ short s_x[XSLOT*MROW*8];   // x chunk (64 steps) + slot 64 = AR "cur"
  __shared__ short s_wih0[512*8];       // w_ih0 bf16, K padded 6->8
  __shared__ float s_h1f[MROW*FP];      // fp32 h1 for the fc head
  __shared__ float s_fcw[ISZ*HSZ];
  __shared__ float s_fcb[8];
  __shared__ short s_zpad[8];           // 16B of zeros for padded fragments

  const int tid  = threadIdx.x;
  const int wv   = tid >> 6;
  const int lane = tid & 63;
  const int l15  = lane & 15;
  const int lq   = lane >> 4;
  const int U    = wv * 16;
  const int u    = U + l15;             // this lane's hidden unit (acc/B-frag col)
  const int row0 = blockIdx.x * MROW;

  // ---- zero / stage LDS ----
  {
    short* p0 = &s_h0[0][0];
    short* p1 = &s_h1[0][0];
    for (int i = tid; i < 2*MROW*HP; i += 512){ p0[i] = 0; p1[i] = 0; }
    for (int i = tid; i < 65*MROW*8; i += 512) s_x[i] = 0;
    if (tid < 8){ s_zpad[tid] = 0; s_fcb[tid] = (tid < 6) ? fc_b[tid] : 0.f; }
    for (int i = tid; i < ISZ*HSZ; i += 512) s_fcw[i] = fc_w[i];
    {
      #pragma unroll
      for (int k = 0; k < 6; k++) s_wih0[tid*8 + k] = f2bf(w_ih0[tid*6 + k]);
      s_wih0[tid*8 + 6] = 0; s_wih0[tid*8 + 7] = 0;
    }
  }

  // ---- weights -> registers (bf16 B-fragments) ----
  // B-frag for 16x16x32: col n = lane&15, k = (lane>>4)*8 + i  (B[k][n] = W[n][k])
  bf16x8 whh0f[4][4], wih1f[4][4], whh1f[4][4];
  float bias0[4], bias1[4];
  #pragma unroll
  for (int g = 0; g < 4; g++){
    const int c = g*128 + u;
    bias0[g] = b_ih0[c] + b_hh0[c];
    bias1[g] = b_ih1[c] + b_hh1[c];
    #pragma unroll
    for (int kt = 0; kt < 4; kt++){
      const int off = c*HSZ + kt*32 + lq*8;
      bf16x8 r0, r1, r2;
      #pragma unroll
      for (int i = 0; i < 8; i++){
        r0[i] = f2bf(w_hh0[off + i]);
        r1[i] = f2bf(w_ih1[off + i]);
        r2[i] = f2bf(w_hh1[off + i]);
      }
      whh0f[g][kt] = r0; wih1f[g][kt] = r1; whh1f[g][kt] = r2;
    }
  }

  float c0[4] = {0.f,0.f,0.f,0.f}, c1[4] = {0.f,0.f,0.f,0.f};
  __syncthreads();

  for (int t = 0; t < SEQ + PRED; ++t){
    // ---- anti-spill: weights "redefined" each iteration (no insts emitted) --
    #pragma unroll
    for (int g = 0; g < 4; g++){
      #pragma unroll
      for (int kt = 0; kt < 4; kt++){
        PIN(whh0f[g][kt]); PIN(wih1f[g][kt]); PIN(whh1f[g][kt]);
      }
    }

    // ---- stage 64 timesteps of x into LDS (bf16, K-padded) ----
    if (t < SEQ && (t & 63) == 0){
      for (int i = tid; i < MROW*64*ISZ; i += 512){
        const int r   = i / (64*ISZ);
        const int rem = i % (64*ISZ);
        const int ts  = rem / ISZ;
        const int k   = rem % ISZ;
        const float v = x[(size_t)(row0 + r)*(SEQ*ISZ) + (size_t)(t + ts)*ISZ + k];
        s_x[(ts*MROW + r)*8 + k] = f2bf(v);
      }
      __syncthreads();
    }
    const int tt = (t < SEQ) ? (t & 63) : 64;
    const int pb = t & 1, qb = pb ^ 1;

    // ---- layer 0: gates = x_t @ w_ih0^T + h0 @ w_hh0^T + b0 ----
    const short* pax = (lq == 0) ? (s_x + (tt*MROW + l15)*8) : s_zpad;
    const bf16x8 ax = *(const bf16x8*)pax;

    f32x4 acc[4];
    #pragma unroll
    for (int g = 0; g < 4; g++){
      const short* pw = (lq == 0) ? (s_wih0 + (g*128 + u)*8) : s_zpad;
      const bf16x8 bw = *(const bf16x8*)pw;
      f32x4 ci; ci[0] = bias0[g]; ci[1] = bias0[g]; ci[2] = bias0[g]; ci[3] = bias0[g];
      acc[g] = __builtin_amdgcn_mfma_f32_16x16x32_bf16(ax, bw, ci, 0, 0, 0);
    }
    #pragma unroll
    for (int kt = 0; kt < 4; kt++){
      const int s = kt*4 + lq;
      const short* pa = s_h0[qb] + l15*HP + s*8;
      const bf16x8 a = *(const bf16x8*)pa;
      #pragma unroll
      for (int g = 0; g < 4; g++)
        acc[g] = __builtin_amdgcn_mfma_f32_16x16x32_bf16(a, whh0f[g][kt], acc[g], 0, 0, 0);
    }
    #pragma unroll
    for (int j = 0; j < 4; j++){
      const float iv = sigf(acc[0][j]);
      const float fv = sigf(acc[1][j]);
      const float gv = tanhf_(acc[2][j]);
      const float ov = sigf(acc[3][j]);
      c0[j] = fv*c0[j] + iv*gv;
      const float h = ov * tanhf_(c0[j]);
      const int r = lq*4 + j;
      s_h0[pb][r*HP + u] = f2bf(h);
    }
    __syncthreads();

    // ---- layer 1: gates = h0_new @ w_ih1^T + h1 @ w_hh1^T + b1 ----
    #pragma unroll
    for (int g = 0; g < 4; g++){
      acc[g][0] = bias1[g]; acc[g][1] = bias1[g]; acc[g][2] = bias1[g]; acc[g][3] = bias1[g];
    }
    #pragma unroll
    for (int kt = 0; kt < 4; kt++){
      const int s = kt*4 + lq;
      const short* pa = s_h0[pb] + l15*HP + s*8;
      const bf16x8 a = *(const bf16x8*)pa;
      #pragma unroll
      for (int g = 0; g < 4; g++)
        acc[g] = __builtin_amdgcn_mfma_f32_16x16x32_bf16(a, wih1f[g][kt], acc[g], 0, 0, 0);
    }
    #pragma unroll
    for (int kt = 0; kt < 4; kt++){
      const int s = kt*4 + lq;
      const short* pa = s_h1[qb] + l15*HP + s*8;
      const bf16x8 a = *(const bf16x8*)pa;
      #pragma unroll
      for (int g = 0; g < 4; g++)
        acc[g] = __builtin_amdgcn_mfma_f32_16x16x32_bf16(a, whh1f[g][kt], acc[g], 0, 0, 0);
    }
    const bool dofc = (t >= SEQ - 1);
    #pragma unroll
    for (int j = 0; j < 4; j++){
      const float iv = sigf(acc[0][j]);
      const float fv = sigf(acc[1][j]);
      const float gv = tanhf_(acc[2][j]);
      const float ov = sigf(acc[3][j]);
      c1[j] = fv*c1[j] + iv*gv;
      const float h = ov * tanhf_(c1[j]);
      const int r = lq*4 + j;
      s_h1[pb][r*HP + u] = f2bf(h);
      if (dofc) s_h1f[r*FP + u] = h;
    }
    __syncthreads();

    // ---- fc head: pred = tanh(h1 @ fc_w^T + fc_b); feeds AR input ----
    if (dofc){
      if (tid < 96){
        const int r  = tid / 6;
        const int ii = tid % 6;
        const f32x4* hv = (const f32x4*)(s_h1f + r*FP);
        const f32x4* wf = (const f32x4*)(s_fcw + ii*128);
        float sacc = 0.f;
        #pragma unroll
        for (int kk = 0; kk < 32; kk++){
          const f32x4 a = hv[kk], b = wf[kk];
          sacc += a[0]*b[0] + a[1]*b[1] + a[2]*b[2] + a[3]*b[3];
        }
        const float pred = tanhf_(s_fcb[ii] + sacc);
        s_x[(64*MROW + r)*8 + ii] = f2bf(pred);   // next step's input
        if (t >= SEQ)
          out[(size_t)(row0 + r)*(PRED*ISZ) + (size_t)(t - SEQ)*ISZ + ii] = pred;
      }
      __syncthreads();
    }
  }
}

extern "C" void kernel_launch(void* const* d_in, const int* in_sizes, int n_in,
                              void* d_out, int out_size, void* d_ws, size_t ws_size,
                              hipStream_t stream) {
  const float* x     = (const float*)d_in[0];
  const float* w_ih0 = (const float*)d_in[1];
  const float* w_hh0 = (const float*)d_in[2];
  const float* b_ih0 = (const float*)d_in[3];
  const float* b_hh0 = (const float*)d_in[4];
  const float* w_ih1 = (const float*)d_in[5];
  const float* w_hh1 = (const float*)d_in[6];
  const float* b_ih1 = (const float*)d_in[7];
  const float* b_hh1 = (const float*)d_in[8];
  const float* fc_w  = (const float*)d_in[9];
  const float* fc_b  = (const float*)d_in[10];
  float* out = (float*)d_out;

  const int Btot = in_sizes[0] / (SEQ * ISZ);   // 4096
  const int nblk = Btot / MROW;                 // 256

  lstm_ar<<<dim3(nblk), dim3(512), 0, stream>>>(
      x, w_ih0, w_hh0, b_ih0, b_hh0, w_ih1, w_hh1, b_ih1, b_hh1, fc_w, fc_b, out);
}

// Round 11
// 3207.447 us; speedup vs baseline: 2.3297x; 1.1459x over previous
//
#include <hip/hip_runtime.h>

#define SEQ 1024
#define ISZ 6
#define HSZ 128
#define PRED 50
#define MROW 16
#define HP   136      // h row pitch in shorts (272B)
#define XCH  8        // x chunk: 8 timesteps staged at a time
#define WSB  131072   // bytes of d_ws needed for pre-converted bf16 whh0

using f32x4  = __attribute__((ext_vector_type(4))) float;
using bf16x8 = __attribute__((ext_vector_type(8))) short;

__device__ __forceinline__ short f2bf(float f){
  union { float f; unsigned u; } v; v.f = f;
  unsigned r = v.u + 0x7FFFu + ((v.u >> 16) & 1u);
  return (short)(r >> 16);
}
__device__ __forceinline__ float bf2f(unsigned short us){
  union { unsigned u; float f; } v; v.u = ((unsigned)us) << 16; return v.f;
}
__device__ __forceinline__ float sigf(float x){
  float e = __builtin_amdgcn_exp2f(x * -1.4426950408889634f);
  return __builtin_amdgcn_rcpf(1.0f + e);
}
__device__ __forceinline__ float tanhf_(float x){
  float e = __builtin_amdgcn_exp2f(x * 2.8853900817779268f);
  return 1.0f - 2.0f * __builtin_amdgcn_rcpf(1.0f + e);
}

#define PIN(v) asm volatile("" : "+v"(v))

// ROUND 11 RESTRUCTURE. Law from r1-r10: register grant = 65536/block_threads,
// immutable. 393KB of weights can NEVER be register-resident (grant = 256KB).
// New split:
//   wih1 -> 64 VGPRs (PINned)          : total pressure ~124 <= 128 grant
//   whh1 -> LDS 131KB (frag-packed, XOR-swizzled; b128 reads at the 8-cyc min)
//   whh0 -> streamed from L2 every step (bf16 pre-packed into d_ws at init;
//           every thread reads exactly the bytes it wrote -> self-coherent;
//           fallback converts f32 inline if ws_size < WSB)
// LDS total 158.8KB -> 1 block/CU, 2 waves/SIMD. Expected bound: LDS pipe
// (~29 b128 reads/thread/step ~ 0.78us/step) with VALU/MFMA/stream hidden.
template<int PRECVT>
__global__
__attribute__((amdgpu_flat_work_group_size(512, 512)))
void lstm_ar(
    const float* __restrict__ x,
    const float* __restrict__ w_ih0, const float* __restrict__ w_hh0,
    const float* __restrict__ b_ih0, const float* __restrict__ b_hh0,
    const float* __restrict__ w_ih1, const float* __restrict__ w_hh1,
    const float* __restrict__ b_ih1, const float* __restrict__ b_hh1,
    const float* __restrict__ fc_w, const float* __restrict__ fc_b,
    float* __restrict__ out, unsigned short* __restrict__ wsb)
{
  __shared__ short s_whh1[65536];          // 131072B frag-packed whh1 (bf16)
  __shared__ short s_h0[2][MROW*HP];       // h0 double buffer
  __shared__ short s_h1[MROW*HP];          // h1 single buffer
  __shared__ short s_x[(XCH+1)*MROW*8];    // x chunk + AR "cur" slot
  __shared__ short s_wih0[512*8];          // w_ih0 bf16, K padded 6->8
  __shared__ float s_bias[2*512];          // b0, b1 pre-summed
  __shared__ float s_fcb[8];
  __shared__ short s_zpad[8];

  const int tid  = threadIdx.x;
  const int wv   = tid >> 6;
  const int lane = tid & 63;
  const int l15  = lane & 15;
  const int lq   = lane >> 4;
  const int u    = wv*16 + l15;            // this lane's hidden unit
  const int row0 = blockIdx.x * MROW;
  char* const whh1b = (char*)s_whh1;

  // ---- init: zero buffers, stage constants ----
  for (int i = tid; i < 2*MROW*HP; i += 512) (&s_h0[0][0])[i] = 0;
  for (int i = tid; i < MROW*HP;   i += 512) s_h1[i] = 0;
  for (int i = tid; i < (XCH+1)*MROW*8; i += 512) s_x[i] = 0;
  if (tid < 8){ s_zpad[tid] = 0; s_fcb[tid] = (tid < 6) ? fc_b[tid] : 0.f; }
  {
    #pragma unroll
    for (int k = 0; k < 6; k++) s_wih0[tid*8 + k] = f2bf(w_ih0[tid*6 + k]);
    s_wih0[tid*8 + 6] = 0; s_wih0[tid*8 + 7] = 0;
  }
  for (int i = tid; i < 1024; i += 512)
    s_bias[i] = (i < 512) ? (b_ih0[i] + b_hh0[i]) : (b_ih1[i-512] + b_hh1[i-512]);

  // whh1 -> LDS frag-pack: byte addr = c*256 + k4*4  XOR ((c&7)<<4)
  for (int i = tid; i < 32768; i += 512){
    const int c = i >> 6, kp = i & 63;
    const unsigned lo = (unsigned short)f2bf(w_hh1[c*128 + 2*kp]);
    const unsigned hi = (unsigned short)f2bf(w_hh1[c*128 + 2*kp + 1]);
    *(unsigned*)(whh1b + ((i*4) ^ ((c & 7) << 4))) = lo | (hi << 16);
  }

  // whh0 -> d_ws as bf16 frags (each thread writes the slots it will read)
  if (PRECVT){
    #pragma unroll
    for (int g = 0; g < 4; g++){
      const int c = g*128 + u;
      #pragma unroll
      for (int kt = 0; kt < 4; kt++){
        const float* wp = w_hh0 + c*HSZ + kt*32 + lq*8;
        bf16x8 f;
        #pragma unroll
        for (int i = 0; i < 8; i++) f[i] = f2bf(wp[i]);
        *(bf16x8*)(wsb + (((wv*4 + g)*4 + kt)*64 + lane)*8) = f;
      }
    }
  }

  // wih1 -> registers (PINned each step)
  bf16x8 wih1f[4][4];
  #pragma unroll
  for (int g = 0; g < 4; g++){
    const int c = g*128 + u;
    #pragma unroll
    for (int kt = 0; kt < 4; kt++){
      const float* wp = w_ih1 + c*HSZ + kt*32 + lq*8;
      bf16x8 f;
      #pragma unroll
      for (int i = 0; i < 8; i++) f[i] = f2bf(wp[i]);
      wih1f[g][kt] = f;
    }
  }

  float c0[4] = {0.f,0.f,0.f,0.f}, c1[4] = {0.f,0.f,0.f,0.f};
  volatile const float* vb = s_bias;       // volatile: block bias-hoist to regs
  __syncthreads();

  for (int t = 0; t < SEQ + PRED; ++t){
    #pragma unroll
    for (int g = 0; g < 4; g++){
      #pragma unroll
      for (int kt = 0; kt < 4; kt++) PIN(wih1f[g][kt]);
    }

    // ---- stage XCH timesteps of x ----
    if (t < SEQ && (t & (XCH-1)) == 0){
      for (int i = tid; i < XCH*MROW*ISZ; i += 512){
        const int r = i / (XCH*ISZ), rem = i % (XCH*ISZ);
        const int ts = rem / ISZ, k = rem % ISZ;
        s_x[(ts*MROW + r)*8 + k] =
          f2bf(x[(size_t)(row0 + r)*(SEQ*ISZ) + (size_t)(t + ts)*ISZ + k]);
      }
      __syncthreads();
    }
    const int tt = (t < SEQ) ? (t & (XCH-1)) : XCH;
    const int pb = t & 1, qb = pb ^ 1;

    // ---- layer 0: x@wih0 + h0@whh0(streamed) + b0 ----
    const bf16x8 ax = *(const bf16x8*)((lq == 0) ? (s_x + (tt*MROW + l15)*8) : s_zpad);
    f32x4 acc[4];
    #pragma unroll
    for (int g = 0; g < 4; g++){
      const bf16x8 bw = *(const bf16x8*)((lq == 0) ? (s_wih0 + (g*128 + u)*8) : s_zpad);
      const float bg = vb[g*128 + u];
      f32x4 ci; ci[0] = bg; ci[1] = bg; ci[2] = bg; ci[3] = bg;
      acc[g] = __builtin_amdgcn_mfma_f32_16x16x32_bf16(ax, bw, ci, 0, 0, 0);
    }
    #pragma unroll
    for (int kt = 0; kt < 4; kt++){
      bf16x8 stg[4];
      if (PRECVT){
        #pragma unroll
        for (int g = 0; g < 4; g++)
          stg[g] = *(const bf16x8*)(wsb + (((wv*4 + g)*4 + kt)*64 + lane)*8);
      } else {
        #pragma unroll
        for (int g = 0; g < 4; g++){
          const float* wp = w_hh0 + (g*128 + u)*HSZ + kt*32 + lq*8;
          bf16x8 f;
          #pragma unroll
          for (int i = 0; i < 8; i++) f[i] = f2bf(wp[i]);
          stg[g] = f;
        }
      }
      const bf16x8 a = *(const bf16x8*)(s_h0[qb] + l15*HP + (kt*4 + lq)*8);
      #pragma unroll
      for (int g = 0; g < 4; g++)
        acc[g] = __builtin_amdgcn_mfma_f32_16x16x32_bf16(a, stg[g], acc[g], 0, 0, 0);
    }
    #pragma unroll
    for (int j = 0; j < 4; j++){
      const float iv = sigf(acc[0][j]);
      const float fv = sigf(acc[1][j]);
      const float gv = tanhf_(acc[2][j]);
      const float ov = sigf(acc[3][j]);
      c0[j] = fv*c0[j] + iv*gv;
      const float h = ov * tanhf_(c0[j]);
      s_h0[pb][(lq*4 + j)*HP + u] = f2bf(h);
    }
    __syncthreads();                       // B2: h0-new visible

    // ---- layer 1: h0new@wih1(regs) + h1@whh1(LDS) + b1 ----
    #pragma unroll
    for (int g = 0; g < 4; g++){
      const float bg = vb[512 + g*128 + u];
      acc[g][0] = bg; acc[g][1] = bg; acc[g][2] = bg; acc[g][3] = bg;
    }
    #pragma unroll
    for (int kt = 0; kt < 4; kt++){
      const bf16x8 a = *(const bf16x8*)(s_h0[pb] + l15*HP + (kt*4 + lq)*8);
      #pragma unroll
      for (int g = 0; g < 4; g++)
        acc[g] = __builtin_amdgcn_mfma_f32_16x16x32_bf16(a, wih1f[g][kt], acc[g], 0, 0, 0);
    }
    #pragma unroll
    for (int kt = 0; kt < 4; kt++){
      const bf16x8 a = *(const bf16x8*)(s_h1 + l15*HP + (kt*4 + lq)*8);
      #pragma unroll
      for (int g = 0; g < 4; g++){
        const int c = g*128 + u;
        const bf16x8 b = *(const bf16x8*)(whh1b +
            ((c*256 + (kt*4 + lq)*16) ^ ((u & 7) << 4)));
        acc[g] = __builtin_amdgcn_mfma_f32_16x16x32_bf16(a, b, acc[g], 0, 0, 0);
      }
    }
    __syncthreads();                       // B3: all h1-old reads done
    const bool dofc = (t >= SEQ - 1);
    #pragma unroll
    for (int j = 0; j < 4; j++){
      const float iv = sigf(acc[0][j]);
      const float fv = sigf(acc[1][j]);
      const float gv = tanhf_(acc[2][j]);
      const float ov = sigf(acc[3][j]);
      c1[j] = fv*c1[j] + iv*gv;
      const float h = ov * tanhf_(c1[j]);
      s_h1[(lq*4 + j)*HP + u] = f2bf(h);
    }

    // ---- fc head (AR phase): pred = tanh(h1 @ fc_w^T + fc_b) ----
    if (dofc){
      __syncthreads();                     // B4: h1-new visible
      if (tid < 96){
        const int r = tid / 6, ii = tid % 6;
        float sacc = 0.f;
        #pragma unroll 4
        for (int kk = 0; kk < 128; kk++)
          sacc += bf2f((unsigned short)s_h1[r*HP + kk]) * fc_w[ii*128 + kk];
        const float pred = tanhf_(s_fcb[ii] + sacc);
        s_x[(XCH*MROW + r)*8 + ii] = f2bf(pred);
        if (t >= SEQ)
          out[(size_t)(row0 + r)*(PRED*ISZ) + (size_t)(t - SEQ)*ISZ + ii] = pred;
      }
      __syncthreads();                     // B5: pred visible for next step
    }
  }
}

extern "C" void kernel_launch(void* const* d_in, const int* in_sizes, int n_in,
                              void* d_out, int out_size, void* d_ws, size_t ws_size,
                              hipStream_t stream) {
  const float* x     = (const float*)d_in[0];
  const float* w_ih0 = (const float*)d_in[1];
  const float* w_hh0 = (const float*)d_in[2];
  const float* b_ih0 = (const float*)d_in[3];
  const float* b_hh0 = (const float*)d_in[4];
  const float* w_ih1 = (const float*)d_in[5];
  const float* w_hh1 = (const float*)d_in[6];
  const float* b_ih1 = (const float*)d_in[7];
  const float* b_hh1 = (const float*)d_in[8];
  const float* fc_w  = (const float*)d_in[9];
  const float* fc_b  = (const float*)d_in[10];
  float* out = (float*)d_out;
  unsigned short* wsb = (unsigned short*)d_ws;

  const int Btot = in_sizes[0] / (SEQ * ISZ);   // 4096
  const int nblk = Btot / MROW;                 // 256

  if (ws_size >= (size_t)WSB)
    lstm_ar<1><<<dim3(nblk), dim3(512), 0, stream>>>(
        x, w_ih0, w_hh0, b_ih0, b_hh0, w_ih1, w_hh1, b_ih1, b_hh1,
        fc_w, fc_b, out, wsb);
  else
    lstm_ar<0><<<dim3(nblk), dim3(512), 0, stream>>>(
        x, w_ih0, w_hh0, b_ih0, b_hh0, w_ih1, w_hh1, b_ih1, b_hh1,
        fc_w, fc_b, out, wsb);
}

// Round 13
// 3206.728 us; speedup vs baseline: 2.3302x; 1.0002x over previous
//
#include <hip/hip_runtime.h>

#define SEQ 1024
#define ISZ 6
#define HSZ 128
#define PRED 50
#define MROW 16
#define HP   136
#define XCH  8
#define NS   2
#define TSTEPS (SEQ + PRED)

// d_ws layout (pipe mode)
#define F_H0   ((size_t)0)
#define F_CUR  ((size_t)32768)
#define F_CONS ((size_t)65536)
#define F_ABT  ((size_t)98304)
#define FLAGBYTES ((size_t)98432)
#define R_H0   FLAGBYTES                            // 256*NS*4096 = 2 MB
#define R_CUR  (R_H0 + (size_t)256*NS*4096)         // 256*NS*256
#define R_W1   (R_CUR + (size_t)256*NS*256)         // wih1 kt2,3 bf16: 65536 B
#define WS_NEED (R_W1 + (size_t)65536)

// LDS pool offsets (uniform 77632B/block -> 2 blocks/CU)
#define OW1    0        // L1: wih1 kt0,1 swizzled (65536)
#define OLAND  65536    // L1: landed h0 (4352)
#define OH1    69888    // L1: h1 (4352)
#define OFCW   74240    // L1: fc_w f32 (3072)
#define OCT    77312    // L1: cur tile (256)
#define OFCB   77568    // L1: fc_b (32)
#define OZP1   77600    // L1: zero pad (16)
#define OH0    0        // L0: h0 dbuf (8704)
#define OX     8704     // L0: x chunk (2048)
#define OWIH0  10752    // L0: wih0 (8192)
#define OZP0   18944    // L0: zero pad (16)
#define POOLB  77632

using f32x4  = __attribute__((ext_vector_type(4))) float;
using bf16x8 = __attribute__((ext_vector_type(8))) short;

__device__ __forceinline__ short f2bf(float f){
  union { float f; unsigned u; } v; v.f = f;
  unsigned r = v.u + 0x7FFFu + ((v.u >> 16) & 1u);
  return (short)(r >> 16);
}
__device__ __forceinline__ float bf2f(unsigned short us){
  union { unsigned u; float f; } v; v.u = ((unsigned)us) << 16; return v.f;
}
__device__ __forceinline__ float sigf(float x){
  float e = __builtin_amdgcn_exp2f(x * -1.4426950408889634f);
  return __builtin_amdgcn_rcpf(1.0f + e);
}
__device__ __forceinline__ float tanhf_(float x){
  float e = __builtin_amdgcn_exp2f(x * 2.8853900817779268f);
  return 1.0f - 2.0f * __builtin_amdgcn_rcpf(1.0f + e);
}
#define PIN(v) asm volatile("" : "+v"(v))

__device__ __forceinline__ int aldf(const int* p){
  return __hip_atomic_load(p, __ATOMIC_ACQUIRE, __HIP_MEMORY_SCOPE_AGENT);
}
__device__ __forceinline__ void astf(int* p, int v){
  __hip_atomic_store(p, v, __ATOMIC_RELEASE, __HIP_MEMORY_SCOPE_AGENT);
}
__device__ __forceinline__ unsigned long long ald64(const void* p){
  return __hip_atomic_load((const unsigned long long*)p, __ATOMIC_RELAXED, __HIP_MEMORY_SCOPE_AGENT);
}
__device__ __forceinline__ void ast64(void* p, unsigned long long v){
  __hip_atomic_store((unsigned long long*)p, v, __ATOMIC_RELAXED, __HIP_MEMORY_SCOPE_AGENT);
}
__device__ __forceinline__ void ast32(void* p, unsigned v){
  __hip_atomic_store((unsigned*)p, v, __ATOMIC_RELAXED, __HIP_MEMORY_SCOPE_AGENT);
}
// spin-wait with sticky abort: a deadlock converts to a fast garbage-finish
// (absmax fail + counters) instead of a 600s harness timeout (round-12 lesson).
__device__ __forceinline__ void waitge(const int* f, int v, int* abt){
  if (threadIdx.x == 0){
    int n = 0;
    while (aldf(f) < v){
      if (aldf(abt)) break;
      __builtin_amdgcn_s_sleep(8);
      if (++n > (1 << 21)){ astf(abt, 1); break; }
    }
  }
  __syncthreads();
}

// 512 blocks = 256 L0 (layer0: whh0 64 regs + wih0 LDS, no streaming) +
// 256 L1 (layer1+fc: whh1 64 regs, wih1 kt0/1 in 64KB LDS, kt2/3 streamed).
// Uniform 77.6KB LDS + 128-reg law -> exactly 2 blocks/CU -> all 512
// resident (verified host-side via occupancy query before launching).
__global__
__attribute__((amdgpu_flat_work_group_size(512, 512)))
void lstm_pipe(
    const float* __restrict__ x,
    const float* __restrict__ w_ih0, const float* __restrict__ w_hh0,
    const float* __restrict__ b_ih0, const float* __restrict__ b_hh0,
    const float* __restrict__ w_ih1, const float* __restrict__ w_hh1,
    const float* __restrict__ b_ih1, const float* __restrict__ b_hh1,
    const float* __restrict__ fc_w, const float* __restrict__ fc_b,
    float* __restrict__ out, char* __restrict__ ws)
{
  __shared__ __align__(16) char pool[POOLB];

  const int tid  = threadIdx.x;
  const int wv   = tid >> 6;
  const int lane = tid & 63;
  const int l15  = lane & 15;
  const int lq   = lane >> 4;
  const int u    = wv*16 + l15;
  const int type = blockIdx.x >> 8;
  const int p    = blockIdx.x & 255;
  const int row0 = p * MROW;

  int* h0f     = (int*)(ws + F_H0   + (size_t)p*128);
  int* curf    = (int*)(ws + F_CUR  + (size_t)p*128);
  int* consf   = (int*)(ws + F_CONS + (size_t)p*128);
  int* abt     = (int*)(ws + F_ABT);
  char* h0ring = ws + R_H0  + (size_t)p*(NS*4096);
  char* curring= ws + R_CUR + (size_t)p*(NS*256);
  short* w1p   = (short*)(ws + R_W1);

  if (type == 0){
    // ================= L0: layer 0, fully resident =================
    short* s_h0   = (short*)(pool + OH0);
    short* s_x    = (short*)(pool + OX);
    short* s_wih0 = (short*)(pool + OWIH0);
    short* s_zp   = (short*)(pool + OZP0);

    for (int i = tid; i < 2*MROW*HP; i += 512) s_h0[i] = 0;
    for (int i = tid; i < XCH*MROW*8; i += 512) s_x[i] = 0;
    if (tid < 8) s_zp[tid] = 0;
    {
      #pragma unroll
      for (int k = 0; k < 6; k++) s_wih0[tid*8 + k] = f2bf(w_ih0[tid*6 + k]);
      s_wih0[tid*8 + 6] = 0; s_wih0[tid*8 + 7] = 0;
    }
    bf16x8 whh0f[4][4];
    float bias0[4];
    #pragma unroll
    for (int g = 0; g < 4; g++){
      const int c = g*128 + u;
      bias0[g] = b_ih0[c] + b_hh0[c];
      #pragma unroll
      for (int kt = 0; kt < 4; kt++){
        const float* wp = w_hh0 + c*HSZ + kt*32 + lq*8;
        bf16x8 f;
        #pragma unroll
        for (int i = 0; i < 8; i++) f[i] = f2bf(wp[i]);
        whh0f[g][kt] = f;
      }
    }
    float c0[4] = {0.f,0.f,0.f,0.f};
    __syncthreads();

    for (int t = 0; t < TSTEPS; ++t){
      #pragma unroll
      for (int g = 0; g < 4; g++){
        #pragma unroll
        for (int kt = 0; kt < 4; kt++) PIN(whh0f[g][kt]);
      }
      if (t >= NS) waitge(consf, t - NS + 1, abt);

      bf16x8 ax;
      if (t < SEQ){
        if ((t & (XCH-1)) == 0){
          for (int i = tid; i < XCH*MROW*ISZ; i += 512){
            const int r = i / (XCH*ISZ), rem = i % (XCH*ISZ);
            const int ts = rem / ISZ, k = rem % ISZ;
            s_x[(ts*MROW + r)*8 + k] =
              f2bf(x[(size_t)(row0 + r)*(SEQ*ISZ) + (size_t)(t + ts)*ISZ + k]);
          }
          __syncthreads();
        }
        ax = *(const bf16x8*)((lq == 0) ? (s_x + ((t & (XCH-1))*MROW + l15)*8) : s_zp);
      } else {
        waitge(curf, t - SEQ + 1, abt);
        if (lq == 0){
          const char* cp = curring + ((t - SEQ) % NS)*256 + l15*16;
          union { unsigned long long q[2]; bf16x8 v; } uu;
          uu.q[0] = ald64(cp); uu.q[1] = ald64(cp + 8);
          ax = uu.v;
        } else ax = *(const bf16x8*)s_zp;
      }

      const int pb = t & 1, qb = pb ^ 1;
      short* h0q = s_h0 + qb*(MROW*HP);
      short* h0p = s_h0 + pb*(MROW*HP);
      f32x4 acc[4];
      #pragma unroll
      for (int g = 0; g < 4; g++){
        const bf16x8 bw = *(const bf16x8*)((lq == 0) ? (s_wih0 + (g*128 + u)*8) : s_zp);
        f32x4 ci; ci[0]=bias0[g]; ci[1]=bias0[g]; ci[2]=bias0[g]; ci[3]=bias0[g];
        acc[g] = __builtin_amdgcn_mfma_f32_16x16x32_bf16(ax, bw, ci, 0, 0, 0);
      }
      #pragma unroll
      for (int kt = 0; kt < 4; kt++){
        const bf16x8 a = *(const bf16x8*)(h0q + l15*HP + (kt*4 + lq)*8);
        #pragma unroll
        for (int g = 0; g < 4; g++)
          acc[g] = __builtin_amdgcn_mfma_f32_16x16x32_bf16(a, whh0f[g][kt], acc[g], 0, 0, 0);
      }
      #pragma unroll
      for (int j = 0; j < 4; j++){
        const float iv = sigf(acc[0][j]);
        const float fv = sigf(acc[1][j]);
        const float gv = tanhf_(acc[2][j]);
        const float ov = sigf(acc[3][j]);
        c0[j] = fv*c0[j] + iv*gv;
        const float h = ov * tanhf_(c0[j]);
        h0p[(lq*4 + j)*HP + u] = f2bf(h);
      }
      __syncthreads();                       // h0(t) complete
      {
        unsigned long long v = *(const unsigned long long*)(h0p + (tid >> 5)*HP + (tid & 31)*4);
        ast64(h0ring + (t % NS)*4096 + tid*8, v);
      }
      __syncthreads();                       // drains ring stores (vmcnt)
      if (tid == 0) astf(h0f, t + 1);
    }
  } else {
    // ================= L1: layer 1 + fc =================
    char*  w1l   = pool + OW1;
    short* s_land= (short*)(pool + OLAND);
    short* s_h1  = (short*)(pool + OH1);
    float* s_fcw = (float*)(pool + OFCW);
    short* s_ct  = (short*)(pool + OCT);
    float* s_fcb = (float*)(pool + OFCB);

    // wih1 kt0,1 -> LDS, XOR-swizzled (r11-proven read path)
    for (int i = tid; i < 16384; i += 512){
      const int c = i >> 5, kp = i & 31;
      const unsigned lo = (unsigned short)f2bf(w_ih1[c*128 + 2*kp]);
      const unsigned hi = (unsigned short)f2bf(w_ih1[c*128 + 2*kp + 1]);
      *(unsigned*)(w1l + ((i*4) ^ ((c & 7) << 4))) = lo | (hi << 16);
    }
    // wih1 kt2,3 -> d_ws pack (each thread reads only what it wrote)
    #pragma unroll
    for (int g = 0; g < 4; g++){
      const int c = g*128 + u;
      #pragma unroll
      for (int ktl = 0; ktl < 2; ktl++){
        const float* wp = w_ih1 + c*HSZ + (2 + ktl)*32 + lq*8;
        bf16x8 f;
        #pragma unroll
        for (int i = 0; i < 8; i++) f[i] = f2bf(wp[i]);
        *(bf16x8*)(w1p + (((wv*4 + g)*2 + ktl)*64 + lane)*8) = f;
      }
    }
    bf16x8 whh1f[4][4];
    float bias1[4];
    #pragma unroll
    for (int g = 0; g < 4; g++){
      const int c = g*128 + u;
      bias1[g] = b_ih1[c] + b_hh1[c];
      #pragma unroll
      for (int kt = 0; kt < 4; kt++){
        const float* wp = w_hh1 + c*HSZ + kt*32 + lq*8;
        bf16x8 f;
        #pragma unroll
        for (int i = 0; i < 8; i++) f[i] = f2bf(wp[i]);
        whh1f[g][kt] = f;
      }
    }
    for (int i = tid; i < MROW*HP; i += 512) s_h1[i] = 0;
    for (int i = tid; i < ISZ*HSZ; i += 512) s_fcw[i] = fc_w[i];
    if (tid < 8) s_fcb[tid] = (tid < 6) ? fc_b[tid] : 0.f;
    if (tid < MROW*8) s_ct[tid] = 0;
    float c1[4] = {0.f,0.f,0.f,0.f};
    __syncthreads();

    for (int t = 0; t < TSTEPS; ++t){
      #pragma unroll
      for (int g = 0; g < 4; g++){
        #pragma unroll
        for (int kt = 0; kt < 4; kt++) PIN(whh1f[g][kt]);
      }
      waitge(h0f, t + 1, abt);
      {
        unsigned long long v = ald64(h0ring + (t % NS)*4096 + tid*8);
        *(unsigned long long*)(s_land + (tid >> 5)*HP + (tid & 31)*4) = v;
      }
      __syncthreads();
      if (tid == 0) astf(consf, t + 1);

      bf16x8 sA[4], sB[4];                   // streamed wih1 kt2,3 (issued early)
      #pragma unroll
      for (int g = 0; g < 4; g++){
        sA[g] = *(const bf16x8*)(w1p + (((wv*4 + g)*2 + 0)*64 + lane)*8);
        sB[g] = *(const bf16x8*)(w1p + (((wv*4 + g)*2 + 1)*64 + lane)*8);
      }
      f32x4 acc[4];
      #pragma unroll
      for (int g = 0; g < 4; g++){
        acc[g][0]=bias1[g]; acc[g][1]=bias1[g]; acc[g][2]=bias1[g]; acc[g][3]=bias1[g];
      }
      #pragma unroll
      for (int kt = 0; kt < 2; kt++){        // wih1 kt0,1 from LDS
        const bf16x8 a = *(const bf16x8*)(s_land + l15*HP + (kt*4 + lq)*8);
        #pragma unroll
        for (int g = 0; g < 4; g++){
          const int c = g*128 + u;
          const bf16x8 b = *(const bf16x8*)(w1l +
              ((c*128 + (kt*4 + lq)*16) ^ ((u & 7) << 4)));
          acc[g] = __builtin_amdgcn_mfma_f32_16x16x32_bf16(a, b, acc[g], 0, 0, 0);
        }
      }
      #pragma unroll
      for (int kt = 0; kt < 4; kt++){        // whh1 from regs
        const bf16x8 a = *(const bf16x8*)(s_h1 + l15*HP + (kt*4 + lq)*8);
        #pragma unroll
        for (int g = 0; g < 4; g++)
          acc[g] = __builtin_amdgcn_mfma_f32_16x16x32_bf16(a, whh1f[g][kt], acc[g], 0, 0, 0);
      }
      {                                      // wih1 kt2,3 streamed
        const bf16x8 a2 = *(const bf16x8*)(s_land + l15*HP + (2*4 + lq)*8);
        #pragma unroll
        for (int g = 0; g < 4; g++)
          acc[g] = __builtin_amdgcn_mfma_f32_16x16x32_bf16(a2, sA[g], acc[g], 0, 0, 0);
        const bf16x8 a3 = *(const bf16x8*)(s_land + l15*HP + (3*4 + lq)*8);
        #pragma unroll
        for (int g = 0; g < 4; g++)
          acc[g] = __builtin_amdgcn_mfma_f32_16x16x32_bf16(a3, sB[g], acc[g], 0, 0, 0);
      }
      __syncthreads();                       // h1(t-1) reads complete
      const bool dofc = (t >= SEQ - 1);
      #pragma unroll
      for (int j = 0; j < 4; j++){
        const float iv = sigf(acc[0][j]);
        const float fv = sigf(acc[1][j]);
        const float gv = tanhf_(acc[2][j]);
        const float ov = sigf(acc[3][j]);
        c1[j] = fv*c1[j] + iv*gv;
        const float h = ov * tanhf_(c1[j]);
        s_h1[(lq*4 + j)*HP + u] = f2bf(h);
      }
      if (dofc){
        __syncthreads();
        if (tid < 96){
          const int r = tid / 6, ii = tid % 6;
          float sacc = 0.f;
          #pragma unroll 4
          for (int kk = 0; kk < 128; kk++)
            sacc += bf2f((unsigned short)s_h1[r*HP + kk]) * s_fcw[ii*128 + kk];
          const float pred = tanhf_(s_fcb[ii] + sacc);
          s_ct[r*8 + ii] = f2bf(pred);
          if (t >= SEQ)
            out[(size_t)(row0 + r)*(PRED*ISZ) + (size_t)(t - SEQ)*ISZ + ii] = pred;
        }
        if (tid < 16){ s_ct[tid*8 + 6] = 0; s_ct[tid*8 + 7] = 0; }
        __syncthreads();
        if (tid < 64)
          ast32(curring + ((t - (SEQ-1)) % NS)*256 + tid*4, ((unsigned*)s_ct)[tid]);
        __syncthreads();
        if (tid == 0) astf(curf, t - SEQ + 2);
      }
    }
  }
}

// ================= fallback: round-11 kernel (proven, 3.2ms) ===============
template<int PRECVT>
__global__
__attribute__((amdgpu_flat_work_group_size(512, 512)))
void lstm_fb(
    const float* __restrict__ x,
    const float* __restrict__ w_ih0, const float* __restrict__ w_hh0,
    const float* __restrict__ b_ih0, const float* __restrict__ b_hh0,
    const float* __restrict__ w_ih1, const float* __restrict__ w_hh1,
    const float* __restrict__ b_ih1, const float* __restrict__ b_hh1,
    const float* __restrict__ fc_w, const float* __restrict__ fc_b,
    float* __restrict__ out, unsigned short* __restrict__ wsb)
{
  __shared__ short s_whh1[65536];
  __shared__ short s_h0[2][MROW*HP];
  __shared__ short s_h1[MROW*HP];
  __shared__ short s_x[(XCH+1)*MROW*8];
  __shared__ short s_wih0[512*8];
  __shared__ float s_bias[2*512];
  __shared__ float s_fcb[8];
  __shared__ short s_zpad[8];

  const int tid  = threadIdx.x;
  const int wv   = tid >> 6;
  const int lane = tid & 63;
  const int l15  = lane & 15;
  const int lq   = lane >> 4;
  const int u    = wv*16 + l15;
  const int row0 = blockIdx.x * MROW;
  char* const whh1b = (char*)s_whh1;

  for (int i = tid; i < 2*MROW*HP; i += 512) (&s_h0[0][0])[i] = 0;
  for (int i = tid; i < MROW*HP;   i += 512) s_h1[i] = 0;
  for (int i = tid; i < (XCH+1)*MROW*8; i += 512) s_x[i] = 0;
  if (tid < 8){ s_zpad[tid] = 0; s_fcb[tid] = (tid < 6) ? fc_b[tid] : 0.f; }
  {
    #pragma unroll
    for (int k = 0; k < 6; k++) s_wih0[tid*8 + k] = f2bf(w_ih0[tid*6 + k]);
    s_wih0[tid*8 + 6] = 0; s_wih0[tid*8 + 7] = 0;
  }
  for (int i = tid; i < 1024; i += 512)
    s_bias[i] = (i < 512) ? (b_ih0[i] + b_hh0[i]) : (b_ih1[i-512] + b_hh1[i-512]);
  for (int i = tid; i < 32768; i += 512){
    const int c = i >> 6, kp = i & 63;
    const unsigned lo = (unsigned short)f2bf(w_hh1[c*128 + 2*kp]);
    const unsigned hi = (unsigned short)f2bf(w_hh1[c*128 + 2*kp + 1]);
    *(unsigned*)(whh1b + ((i*4) ^ ((c & 7) << 4))) = lo | (hi << 16);
  }
  if (PRECVT){
    #pragma unroll
    for (int g = 0; g < 4; g++){
      const int c = g*128 + u;
      #pragma unroll
      for (int kt = 0; kt < 4; kt++){
        const float* wp = w_hh0 + c*HSZ + kt*32 + lq*8;
        bf16x8 f;
        #pragma unroll
        for (int i = 0; i < 8; i++) f[i] = f2bf(wp[i]);
        *(bf16x8*)(wsb + (((wv*4 + g)*4 + kt)*64 + lane)*8) = f;
      }
    }
  }
  bf16x8 wih1f[4][4];
  #pragma unroll
  for (int g = 0; g < 4; g++){
    const int c = g*128 + u;
    #pragma unroll
    for (int kt = 0; kt < 4; kt++){
      const float* wp = w_ih1 + c*HSZ + kt*32 + lq*8;
      bf16x8 f;
      #pragma unroll
      for (int i = 0; i < 8; i++) f[i] = f2bf(wp[i]);
      wih1f[g][kt] = f;
    }
  }
  float c0[4] = {0.f,0.f,0.f,0.f}, c1[4] = {0.f,0.f,0.f,0.f};
  volatile const float* vb = s_bias;
  __syncthreads();

  for (int t = 0; t < TSTEPS; ++t){
    #pragma unroll
    for (int g = 0; g < 4; g++){
      #pragma unroll
      for (int kt = 0; kt < 4; kt++) PIN(wih1f[g][kt]);
    }
    if (t < SEQ && (t & (XCH-1)) == 0){
      for (int i = tid; i < XCH*MROW*ISZ; i += 512){
        const int r = i / (XCH*ISZ), rem = i % (XCH*ISZ);
        const int ts = rem / ISZ, k = rem % ISZ;
        s_x[(ts*MROW + r)*8 + k] =
          f2bf(x[(size_t)(row0 + r)*(SEQ*ISZ) + (size_t)(t + ts)*ISZ + k]);
      }
      __syncthreads();
    }
    const int tt = (t < SEQ) ? (t & (XCH-1)) : XCH;
    const int pb = t & 1, qb = pb ^ 1;

    const bf16x8 ax = *(const bf16x8*)((lq == 0) ? (s_x + (tt*MROW + l15)*8) : s_zpad);
    f32x4 acc[4];
    #pragma unroll
    for (int g = 0; g < 4; g++){
      const bf16x8 bw = *(const bf16x8*)((lq == 0) ? (s_wih0 + (g*128 + u)*8) : s_zpad);
      const float bg = vb[g*128 + u];
      f32x4 ci; ci[0] = bg; ci[1] = bg; ci[2] = bg; ci[3] = bg;
      acc[g] = __builtin_amdgcn_mfma_f32_16x16x32_bf16(ax, bw, ci, 0, 0, 0);
    }
    #pragma unroll
    for (int kt = 0; kt < 4; kt++){
      bf16x8 stg[4];
      if (PRECVT){
        #pragma unroll
        for (int g = 0; g < 4; g++)
          stg[g] = *(const bf16x8*)(wsb + (((wv*4 + g)*4 + kt)*64 + lane)*8);
      } else {
        #pragma unroll
        for (int g = 0; g < 4; g++){
          const float* wp = w_hh0 + (g*128 + u)*HSZ + kt*32 + lq*8;
          bf16x8 f;
          #pragma unroll
          for (int i = 0; i < 8; i++) f[i] = f2bf(wp[i]);
          stg[g] = f;
        }
      }
      const bf16x8 a = *(const bf16x8*)(s_h0[qb] + l15*HP + (kt*4 + lq)*8);
      #pragma unroll
      for (int g = 0; g < 4; g++)
        acc[g] = __builtin_amdgcn_mfma_f32_16x16x32_bf16(a, stg[g], acc[g], 0, 0, 0);
    }
    #pragma unroll
    for (int j = 0; j < 4; j++){
      const float iv = sigf(acc[0][j]);
      const float fv = sigf(acc[1][j]);
      const float gv = tanhf_(acc[2][j]);
      const float ov = sigf(acc[3][j]);
      c0[j] = fv*c0[j] + iv*gv;
      const float h = ov * tanhf_(c0[j]);
      s_h0[pb][(lq*4 + j)*HP + u] = f2bf(h);
    }
    __syncthreads();

    #pragma unroll
    for (int g = 0; g < 4; g++){
      const float bg = vb[512 + g*128 + u];
      acc[g][0] = bg; acc[g][1] = bg; acc[g][2] = bg; acc[g][3] = bg;
    }
    #pragma unroll
    for (int kt = 0; kt < 4; kt++){
      const bf16x8 a = *(const bf16x8*)(s_h0[pb] + l15*HP + (kt*4 + lq)*8);
      #pragma unroll
      for (int g = 0; g < 4; g++)
        acc[g] = __builtin_amdgcn_mfma_f32_16x16x32_bf16(a, wih1f[g][kt], acc[g], 0, 0, 0);
    }
    #pragma unroll
    for (int kt = 0; kt < 4; kt++){
      const bf16x8 a = *(const bf16x8*)(s_h1 + l15*HP + (kt*4 + lq)*8);
      #pragma unroll
      for (int g = 0; g < 4; g++){
        const int c = g*128 + u;
        const bf16x8 b = *(const bf16x8*)(whh1b +
            ((c*256 + (kt*4 + lq)*16) ^ ((u & 7) << 4)));
        acc[g] = __builtin_amdgcn_mfma_f32_16x16x32_bf16(a, b, acc[g], 0, 0, 0);
      }
    }
    __syncthreads();
    const bool dofc = (t >= SEQ - 1);
    #pragma unroll
    for (int j = 0; j < 4; j++){
      const float iv = sigf(acc[0][j]);
      const float fv = sigf(acc[1][j]);
      const float gv = tanhf_(acc[2][j]);
      const float ov = sigf(acc[3][j]);
      c1[j] = fv*c1[j] + iv*gv;
      const float h = ov * tanhf_(c1[j]);
      s_h1[(lq*4 + j)*HP + u] = f2bf(h);
    }
    if (dofc){
      __syncthreads();
      if (tid < 96){
        const int r = tid / 6, ii = tid % 6;
        float sacc = 0.f;
        #pragma unroll 4
        for (int kk = 0; kk < 128; kk++)
          sacc += bf2f((unsigned short)s_h1[r*HP + kk]) * fc_w[ii*128 + kk];
        const float pred = tanhf_(s_fcb[ii] + sacc);
        s_x[(XCH*MROW + r)*8 + ii] = f2bf(pred);
        if (t >= SEQ)
          out[(size_t)(row0 + r)*(PRED*ISZ) + (size_t)(t - SEQ)*ISZ + ii] = pred;
      }
      __syncthreads();
    }
  }
}

extern "C" void kernel_launch(void* const* d_in, const int* in_sizes, int n_in,
                              void* d_out, int out_size, void* d_ws, size_t ws_size,
                              hipStream_t stream) {
  const float* x     = (const float*)d_in[0];
  const float* w_ih0 = (const float*)d_in[1];
  const float* w_hh0 = (const float*)d_in[2];
  const float* b_ih0 = (const float*)d_in[3];
  const float* b_hh0 = (const float*)d_in[4];
  const float* w_ih1 = (const float*)d_in[5];
  const float* w_hh1 = (const float*)d_in[6];
  const float* b_ih1 = (const float*)d_in[7];
  const float* b_hh1 = (const float*)d_in[8];
  const float* fc_w  = (const float*)d_in[9];
  const float* fc_b  = (const float*)d_in[10];
  float* out = (float*)d_out;

  int nb = 0;
  hipError_t oe = hipOccupancyMaxActiveBlocksPerMultiprocessor(&nb, lstm_pipe, 512, 0);
  const bool pipe_ok = (oe == hipSuccess) && (nb >= 2) && (ws_size >= WS_NEED);

  if (pipe_ok){
    hipMemsetAsync(d_ws, 0, FLAGBYTES, stream);
    lstm_pipe<<<dim3(512), dim3(512), 0, stream>>>(
        x, w_ih0, w_hh0, b_ih0, b_hh0, w_ih1, w_hh1, b_ih1, b_hh1,
        fc_w, fc_b, out, (char*)d_ws);
  } else if (ws_size >= (size_t)131072){
    lstm_fb<1><<<dim3(256), dim3(512), 0, stream>>>(
        x, w_ih0, w_hh0, b_ih0, b_hh0, w_ih1, w_hh1, b_ih1, b_hh1,
        fc_w, fc_b, out, (unsigned short*)d_ws);
  } else {
    lstm_fb<0><<<dim3(256), dim3(512), 0, stream>>>(
        x, w_ih0, w_hh0, b_ih0, b_hh0, w_ih1, w_hh1, b_ih1, b_hh1,
        fc_w, fc_b, out, (unsigned short*)d_ws);
  }
}